// Round 1
// baseline (320.884 us; speedup 1.0000x reference)
//
#include <hip/hip_runtime.h>
#include <hip/hip_bf16.h>

#define ALPHA_ 1.0f
#define BETA_  0.5f
#define GAMMA_ 0.3f
#define EPS_   1e-8f

typedef unsigned short u16;
typedef unsigned int u32;

constexpr int B_ = 32, C_ = 256, F_ = 2048;
constexpr int NTOT = B_ * C_ * F_;          // 16777216
constexpr int G8   = NTOT / 8;              // 2097152 groups of 8 elems
constexpr int NCC  = B_ * C_ * C_;          // 2097152
constexpr int NPOS = 10;                    // ti<=tj positions in 4x4 tile grid
constexpr int KSPL = 4;                     // K-split factor (K=2048 -> 4x512)
constexpr int NBLK = B_ * NPOS * KSPL;      // 1280 pci blocks (1280 % 8 == 0)
constexpr int NRED = B_ * NPOS * 64 * 64;   // 1310720 partial re/im elements

// symmetric tile positions: 4 diagonal first, then 6 strict-upper
__constant__ int TI_[NPOS] = {0, 1, 2, 3, 0, 0, 0, 1, 1, 2};
__constant__ int TJ_[NPOS] = {0, 1, 2, 3, 1, 2, 3, 2, 3, 3};

typedef __bf16 bf16x8 __attribute__((ext_vector_type(8)));
typedef float  f32x4  __attribute__((ext_vector_type(4)));

// round-to-nearest-even float -> bf16 bits (sin/cos inputs, no NaN/Inf)
__device__ __forceinline__ u32 f2bf(float x) {
    unsigned u = __float_as_uint(x);
    u += 0x7fffu + ((u >> 16) & 1u);
    return (u >> 16);
}

// async global->LDS, 16 B per lane; LDS dst = wave-uniform base + lane*16
__device__ __forceinline__ void async_copy16(const void* g, void* l) {
    __builtin_amdgcn_global_load_lds(
        (const __attribute__((address_space(1))) unsigned int*)g,
        (__attribute__((address_space(3))) unsigned int*)l,
        16, 0, 0);
}

// ---------------------------------------------------------------------------
// Kernel A: elementwise mag/phase losses + cos/sin(phase_hat) as bf16 in ws.
// 8 elems/thread/group, 2 groups' loads (16x float4) in flight per iter.
// __launch_bounds__(256, 4): allow 128 VGPRs so the 16-deep load pipeline
// is actually kept in flight (default bounds squeezed to 32 VGPR -> ~4-deep
// -> latency-bound at 3.1 TB/s effective).
// ---------------------------------------------------------------------------
__device__ __forceinline__ void ew_body(int g,
    float4 p0, float4 p1, float4 q0, float4 q1,
    float4 a0, float4 a1, float4 b0, float4 b1,
    float& msum, float& psum, int4* __restrict__ cb4, int4* __restrict__ sb4)
{
    float pv[8] = {p0.x, p0.y, p0.z, p0.w, p1.x, p1.y, p1.z, p1.w};
    float qv[8] = {q0.x, q0.y, q0.z, q0.w, q1.x, q1.y, q1.z, q1.w};
    float av[8] = {a0.x, a0.y, a0.z, a0.w, a1.x, a1.y, a1.z, a1.w};
    float bv[8] = {b0.x, b0.y, b0.z, b0.w, b1.x, b1.y, b1.z, b1.w};
    u32 cu[8], su[8];
    #pragma unroll
    for (int j = 0; j < 8; j++) {
        float dm = av[j] - bv[j];
        msum += dm * dm;
        psum += 1.f - __cosf(pv[j] - qv[j]);
        float s, c;
        __sincosf(pv[j], &s, &c);
        cu[j] = f2bf(c);
        su[j] = f2bf(s);
    }
    cb4[g] = make_int4((int)(cu[0] | (cu[1] << 16)), (int)(cu[2] | (cu[3] << 16)),
                       (int)(cu[4] | (cu[5] << 16)), (int)(cu[6] | (cu[7] << 16)));
    sb4[g] = make_int4((int)(su[0] | (su[1] << 16)), (int)(su[2] | (su[3] << 16)),
                       (int)(su[4] | (su[5] << 16)), (int)(su[6] | (su[7] << 16)));
}

__global__ void __launch_bounds__(256, 4)
ew_kernel(const float4* __restrict__ mh, const float4* __restrict__ ph,
          const float4* __restrict__ mt, const float4* __restrict__ pt,
          int4* __restrict__ cb4, int4* __restrict__ sb4,
          float* __restrict__ accum)
{
    __shared__ float sm[4], sp[4];
    const int tid    = blockIdx.x * 256 + threadIdx.x;
    const int stride = 2048 * 256;          // 524288; G8/stride = 4
    float msum = 0.f, psum = 0.f;

    #pragma unroll
    for (int half = 0; half < 2; ++half) {
        int g0 = tid + (2 * half) * stride;
        int g1 = g0 + stride;
        // issue all 16 loads before any compute (needs the 128-VGPR budget)
        float4 p00 = ph[2*g0], p01 = ph[2*g0+1];
        float4 q00 = pt[2*g0], q01 = pt[2*g0+1];
        float4 a00 = mh[2*g0], a01 = mh[2*g0+1];
        float4 b00 = mt[2*g0], b01 = mt[2*g0+1];
        float4 p10 = ph[2*g1], p11 = ph[2*g1+1];
        float4 q10 = pt[2*g1], q11 = pt[2*g1+1];
        float4 a10 = mh[2*g1], a11 = mh[2*g1+1];
        float4 b10 = mt[2*g1], b11 = mt[2*g1+1];
        ew_body(g0, p00, p01, q00, q01, a00, a01, b00, b01, msum, psum, cb4, sb4);
        ew_body(g1, p10, p11, q10, q11, a10, a11, b10, b11, msum, psum, cb4, sb4);
    }

    #pragma unroll
    for (int o = 32; o > 0; o >>= 1) {
        msum += __shfl_down(msum, o, 64);
        psum += __shfl_down(psum, o, 64);
    }
    int lane = threadIdx.x & 63, wv = threadIdx.x >> 6;
    if (lane == 0) { sm[wv] = msum; sp[wv] = psum; }
    __syncthreads();
    if (threadIdx.x == 0) {
        atomicAdd(&accum[0], sm[0] + sm[1] + sm[2] + sm[3]);
        atomicAdd(&accum[1], sp[0] + sp[1] + sp[2] + sp[3]);
    }
}

// ---------------------------------------------------------------------------
// Kernel B: batched MFMA partial re/im for the SYMMETRIC tile set, K-split 4.
// PCI is symmetric (re symmetric, im antisymmetric, |.| symmetric — bitwise,
// same commuted products summed in the same k order), so only the 10 ti<=tj
// 64x64 tile positions are computed: 37.5% fewer MFMAs. K-split x4 lifts the
// grid to 1280 blocks = 5 blocks/CU (LDS 5*32KB = 160KB exactly) vs the old
// 512-block / 2-per-CU launch that left the vmcnt(0)+barrier drain exposed.
// Blocks atomically accumulate un-normalized re and (sc-cs) partials; the
// sqrt/loss epilogue moves to coh_kernel.
// Staging/swizzle/fragment indexing identical to the verified version; the
// K-split only adds a +h*1024 byte offset (8 iters of 128 B per stream).
// ---------------------------------------------------------------------------
__global__ void __launch_bounds__(256)
pci_kernel(const u16* __restrict__ cb, const u16* __restrict__ sb,
           float* __restrict__ reb, float* __restrict__ imb)
{
    __shared__ char lds[32768];          // A tile 16 KB | B tile 16 KB
    char* la = lds;
    char* lb = lds + 16384;

    // bijective XCD swizzle (NBLK % 8 == 0): chunks of 160 logical blocks
    // (4 batches' worth of shared cb/sb panels) per XCD
    const int bid = blockIdx.x;
    const int l   = (bid & 7) * (NBLK / 8) + (bid >> 3);
    const int h   = l & 3;                   // K-split index 0..3
    const int t4  = l >> 2;
    const int pos = t4 % NPOS;               // symmetric tile position
    const int y   = t4 / NPOS;               // batch
    const int i0 = TI_[pos] * 64, j0 = TJ_[pos] * 64;

    const int t    = threadIdx.x;
    const int lane = t & 63, w = t >> 6;
    const int wrow = (w >> 1) * 32, wcol = (w & 1) * 32;
    const int m = lane & 15, q = lane >> 4;

    // staging source pointers: wave w, instr r covers rows w*16+r*4 .. +4,
    // lane covers row += lane>>4, physical chunk p = lane&15.
    // XOR swizzle folded into the per-lane GLOBAL address (direct-to-LDS
    // destination is fixed at base + lane*16). h*1024 selects the K quarter.
    const char* gA[4];
    const char* gB[4];
    {
        const int p = lane & 15;
        #pragma unroll
        for (int r = 0; r < 4; ++r) {
            int row = w * 16 + r * 4 + (lane >> 4);
            int c   = p ^ (row & 15);            // logical chunk
            const u16* arr = (c < 8) ? cb : sb;  // cos | sin stream
            int cc = c & 7;                      // 16B chunk within 128B slab
            gA[r] = (const char*)arr + ((size_t)(y * 256 + i0 + row)) * 4096 + cc * 16 + h * 1024;
            gB[r] = (const char*)arr + ((size_t)(y * 256 + j0 + row)) * 4096 + cc * 16 + h * 1024;
        }
    }

    f32x4 zero = {0.f, 0.f, 0.f, 0.f};
    f32x4 accR[2][2], accSC[2][2], accCS[2][2];
    #pragma unroll
    for (int a = 0; a < 2; a++)
        #pragma unroll
        for (int c = 0; c < 2; c++) {
            accR[a][c] = zero; accSC[a][c] = zero; accCS[a][c] = zero;
        }

    for (int it = 0; it < 8; ++it) {         // 8 iters x BK=64 = K/4
        __syncthreads();                     // protect LDS from prior reads
        #pragma unroll
        for (int r = 0; r < 4; ++r) {
            async_copy16(gA[r], la + w * 4096 + r * 1024);
            async_copy16(gB[r], lb + w * 4096 + r * 1024);
            gA[r] += 128; gB[r] += 128;      // 64 k per iter = 128 B per stream
        }
        __syncthreads();                     // drains vmcnt(0) + barrier

        #pragma unroll
        for (int s = 0; s < 2; ++s) {
            bf16x8 fac[2], fas[2], fbc[2], fbs[2];
            #pragma unroll
            for (int a = 0; a < 2; a++) {
                const char* base = la + (wrow + a * 16 + m) * 256;
                int pc = ((4 * s + q) ^ m) * 16;     // cos physical chunk
                fac[a] = *(const bf16x8*)(base + pc);
                fas[a] = *(const bf16x8*)(base + (pc ^ 128)); // sin = cos ^ bit3
            }
            #pragma unroll
            for (int c = 0; c < 2; c++) {
                const char* base = lb + (wcol + c * 16 + m) * 256;
                int pc = ((4 * s + q) ^ m) * 16;
                fbc[c] = *(const bf16x8*)(base + pc);
                fbs[c] = *(const bf16x8*)(base + (pc ^ 128));
            }
            #pragma unroll
            for (int a = 0; a < 2; a++)
                #pragma unroll
                for (int c = 0; c < 2; c++) {
                    accR[a][c]  = __builtin_amdgcn_mfma_f32_16x16x32_bf16(fac[a], fbc[c], accR[a][c], 0, 0, 0);
                    accR[a][c]  = __builtin_amdgcn_mfma_f32_16x16x32_bf16(fas[a], fbs[c], accR[a][c], 0, 0, 0);
                    accSC[a][c] = __builtin_amdgcn_mfma_f32_16x16x32_bf16(fas[a], fbc[c], accSC[a][c], 0, 0, 0);
                    accCS[a][c] = __builtin_amdgcn_mfma_f32_16x16x32_bf16(fac[a], fbs[c], accCS[a][c], 0, 0, 0);
                }
        }
    }

    // epilogue: atomic partial accumulate of re and (sc-cs); 4-way contention
    // (one per K quarter) per address, spread in time
    const int tb = (y * NPOS + pos) * 4096;
    #pragma unroll
    for (int a = 0; a < 2; a++)
        #pragma unroll
        for (int c = 0; c < 2; c++) {
            int ii = wrow + a * 16 + q * 4;      // C/D: row=(lane>>4)*4+reg
            int jj = wcol + c * 16 + m;          // C/D: col=lane&15
            #pragma unroll
            for (int r = 0; r < 4; r++) {
                int idx = tb + (ii + r) * 64 + jj;
                atomicAdd(&reb[idx], accR[a][c][r]);
                atomicAdd(&imb[idx], accSC[a][c][r] - accCS[a][c][r]);
            }
        }
}

// ---------------------------------------------------------------------------
// Kernel B2: combine re/im partials -> pci -> squared error vs target(s).
// Off-diagonal tiles contribute both (i,j) and (j,i) target terms (pci is
// symmetric, so p is shared). pos is uniform per wave -> no divergence.
// ---------------------------------------------------------------------------
__global__ void __launch_bounds__(256)
coh_kernel(const float* __restrict__ reb, const float* __restrict__ imb,
           const float* __restrict__ tgt, float* __restrict__ accum)
{
    __shared__ float sred[4];
    const int tid  = blockIdx.x * 256 + threadIdx.x;
    const int e0   = tid * 8;                // 8 consecutive elems, one row
    const int tile = e0 >> 12;
    const int y    = tile / NPOS;
    const int pos  = tile % NPOS;
    const int ii   = (e0 & 4095) >> 6;
    const int jj0  = e0 & 63;
    const int ig   = TI_[pos] * 64 + ii;
    const int jg   = TJ_[pos] * 64 + jj0;
    const bool off = (pos >= 4);
    const float invf = 1.0f / (float)F_;
    const float* ty = tgt + (size_t)y * (C_ * C_);
    const float* tr = ty + ig * C_ + jg;

    float4 r0 = *(const float4*)(reb + e0);
    float4 r1 = *(const float4*)(reb + e0 + 4);
    float4 i0 = *(const float4*)(imb + e0);
    float4 i1 = *(const float4*)(imb + e0 + 4);
    float rv[8] = {r0.x, r0.y, r0.z, r0.w, r1.x, r1.y, r1.z, r1.w};
    float iv[8] = {i0.x, i0.y, i0.z, i0.w, i1.x, i1.y, i1.z, i1.w};

    float coh = 0.f;
    #pragma unroll
    for (int j = 0; j < 8; j++) {
        float re = rv[j] * invf, im = iv[j] * invf;
        float p  = sqrtf(re * re + im * im + EPS_);
        float d  = p - tr[j];
        coh += d * d;
        if (off) { float d2 = p - ty[(jg + j) * C_ + ig]; coh += d2 * d2; }
    }

    #pragma unroll
    for (int o = 32; o > 0; o >>= 1) coh += __shfl_down(coh, o, 64);
    int lane = threadIdx.x & 63, w = threadIdx.x >> 6;
    if (lane == 0) sred[w] = coh;
    __syncthreads();
    if (threadIdx.x == 0)
        atomicAdd(&accum[2], sred[0] + sred[1] + sred[2] + sred[3]);
}

// ---------------------------------------------------------------------------
// Kernel C: finalize the 4 scalars
// ---------------------------------------------------------------------------
__global__ void fin_kernel(const float* __restrict__ accum, float* __restrict__ out)
{
    if (threadIdx.x == 0) {
        float mag = accum[0] * (1.0f / (float)NTOT);
        float phs = accum[1] * (1.0f / (float)NTOT);
        float coh = accum[2] * (1.0f / (float)NCC);
        out[0] = ALPHA_ * mag + BETA_ * phs + GAMMA_ * coh;
        out[1] = mag;
        out[2] = phs;
        out[3] = coh;
    }
}

extern "C" void kernel_launch(void* const* d_in, const int* in_sizes, int n_in,
                              void* d_out, int out_size, void* d_ws, size_t ws_size,
                              hipStream_t stream)
{
    const float* mh  = (const float*)d_in[0];
    const float* ph  = (const float*)d_in[1];
    const float* mt  = (const float*)d_in[2];
    const float* pt  = (const float*)d_in[3];
    const float* tgt = (const float*)d_in[4];
    float* out = (float*)d_out;

    // ws layout: [0..3] float accumulators | cb (32 MB) | sb (32 MB)
    //            | reb (5.24 MB) | imb (5.24 MB)
    float* accum = (float*)d_ws;
    u16* cb  = (u16*)((char*)d_ws + 256);
    u16* sb  = cb + (size_t)NTOT;
    float* reb = (float*)(sb + (size_t)NTOT);
    float* imb = reb + NRED;

    hipMemsetAsync(d_ws, 0, 16, stream);
    hipMemsetAsync(reb, 0, (size_t)NRED * 2 * sizeof(float), stream);

    ew_kernel<<<2048, 256, 0, stream>>>(
        (const float4*)mh, (const float4*)ph, (const float4*)mt, (const float4*)pt,
        (int4*)cb, (int4*)sb, accum);

    pci_kernel<<<NBLK, 256, 0, stream>>>(cb, sb, reb, imb);

    coh_kernel<<<640, 256, 0, stream>>>(reb, imb, tgt, accum);

    fin_kernel<<<1, 64, 0, stream>>>(accum, out);
}

// Round 3
// 308.526 us; speedup vs baseline: 1.0401x; 1.0401x over previous
//
#include <hip/hip_runtime.h>
#include <hip/hip_bf16.h>

#define ALPHA_ 1.0f
#define BETA_  0.5f
#define GAMMA_ 0.3f
#define EPS_   1e-8f

typedef unsigned short u16;
typedef unsigned int u32;

constexpr int B_ = 32, C_ = 256, F_ = 2048;
constexpr int NTOT = B_ * C_ * F_;          // 16777216
constexpr int NCC  = B_ * C_ * C_;          // 2097152
constexpr int NPOS = 10;                    // ti<=tj positions in 4x4 tile grid
constexpr int KSPL = 4;                     // K-split factor (K=2048 -> 4x512)
constexpr int NBLK = B_ * NPOS * KSPL;      // 1280 pci blocks (1280 % 8 == 0)
constexpr int NRED = B_ * NPOS * 64 * 64;   // 1310720 partial re/im elements

// symmetric tile positions: 4 diagonal first, then 6 strict-upper
__constant__ int TI_[NPOS] = {0, 1, 2, 3, 0, 0, 0, 1, 1, 2};
__constant__ int TJ_[NPOS] = {0, 1, 2, 3, 1, 2, 3, 2, 3, 3};

typedef __bf16 bf16x8 __attribute__((ext_vector_type(8)));
typedef float  f32x4  __attribute__((ext_vector_type(4)));

// round-to-nearest-even float -> bf16 bits (sin/cos inputs, no NaN/Inf)
__device__ __forceinline__ u32 f2bf(float x) {
    unsigned u = __float_as_uint(x);
    u += 0x7fffu + ((u >> 16) & 1u);
    return (u >> 16);
}

// ---------------------------------------------------------------------------
// Kernel A: elementwise mag/phase losses only (cos/sin staging moved to pci).
// 8 groups/thread, depth-2 software pipeline: sched_barrier(0) FORCES the
// next group's 8 loads to issue before the current group's compute, making
// the 16-deep in-flight load window structural. Round-1 lesson: launch_bounds
// alone doesn't do it (compiler still chose 32 VGPR).
// grid 1024 x 256 = 262144 threads, 8 groups each = G8 groups total.
// ---------------------------------------------------------------------------
__device__ __forceinline__ void ew_body(
    float4 p0, float4 p1, float4 q0, float4 q1,
    float4 a0, float4 a1, float4 b0, float4 b1,
    float& msum, float& psum)
{
    float pv[8] = {p0.x, p0.y, p0.z, p0.w, p1.x, p1.y, p1.z, p1.w};
    float qv[8] = {q0.x, q0.y, q0.z, q0.w, q1.x, q1.y, q1.z, q1.w};
    float av[8] = {a0.x, a0.y, a0.z, a0.w, a1.x, a1.y, a1.z, a1.w};
    float bv[8] = {b0.x, b0.y, b0.z, b0.w, b1.x, b1.y, b1.z, b1.w};
    #pragma unroll
    for (int j = 0; j < 8; j++) {
        float dm = av[j] - bv[j];
        msum += dm * dm;
        psum += 1.f - __cosf(pv[j] - qv[j]);
    }
}

__global__ void __launch_bounds__(256, 4)
ew_kernel(const float4* __restrict__ mh, const float4* __restrict__ ph,
          const float4* __restrict__ mt, const float4* __restrict__ pt,
          float* __restrict__ accum)
{
    __shared__ float sm[4], sp[4];
    const int tid = blockIdx.x * 256 + threadIdx.x;
    constexpr int STR = 1024 * 256;          // 262144 threads; 8 groups each
    float msum = 0.f, psum = 0.f;

    // fully-unrolled arrays -> all indices compile-time; live depth is 2
    // groups (~64 payload VGPRs), the rest coalesce away
    float4 P0[8], P1[8], Q0[8], Q1[8], A0[8], A1[8], B0[8], B1[8];

#define EWLOAD(i) { int g2 = 2 * (tid + (i) * STR);            \
    P0[i] = ph[g2]; P1[i] = ph[g2 + 1];                         \
    Q0[i] = pt[g2]; Q1[i] = pt[g2 + 1];                         \
    A0[i] = mh[g2]; A1[i] = mh[g2 + 1];                         \
    B0[i] = mt[g2]; B1[i] = mt[g2 + 1]; }

    EWLOAD(0);
    #pragma unroll
    for (int i = 0; i < 7; ++i) {
        EWLOAD(i + 1);
        __builtin_amdgcn_sched_barrier(0);   // loads(i+1) pinned above compute(i)
        ew_body(P0[i], P1[i], Q0[i], Q1[i], A0[i], A1[i], B0[i], B1[i], msum, psum);
    }
    ew_body(P0[7], P1[7], Q0[7], Q1[7], A0[7], A1[7], B0[7], B1[7], msum, psum);
#undef EWLOAD

    #pragma unroll
    for (int o = 32; o > 0; o >>= 1) {
        msum += __shfl_down(msum, o, 64);
        psum += __shfl_down(psum, o, 64);
    }
    int lane = threadIdx.x & 63, wv = threadIdx.x >> 6;
    if (lane == 0) { sm[wv] = msum; sp[wv] = psum; }
    __syncthreads();
    if (threadIdx.x == 0) {
        atomicAdd(&accum[0], sm[0] + sm[1] + sm[2] + sm[3]);
        atomicAdd(&accum[1], sp[0] + sp[1] + sp[2] + sp[3]);
    }
}

// ---------------------------------------------------------------------------
// Kernel B: batched MFMA partial re/im, SYMMETRIC tile set, K-split 4.
// Staging reg-staged DIRECTLY from phase_hat (f32): load 8 phases, sincos ->
// bf16 pack -> swizzled ds_write_b128 pair (cos chunk, sin = ^128). Same
// bytes as reading cb/sb (f32 == cos+sin bf16), so ew's 64 MB write and the
// 64 MB ws buffers disappear. LDS physical layout and the MFMA/fragment
// read phase are byte-identical to the round-1-verified kernel.
// Diagonal blocks (i0==j0) stage one panel and read B-fragments from la.
// Epilogue: deterministic per-h slab float2 stores (NO atomics, no memset).
// ---------------------------------------------------------------------------
__device__ __forceinline__ void stage8(float4 a, float4 b, char* base, int pc) {
    float v[8] = {a.x, a.y, a.z, a.w, b.x, b.y, b.z, b.w};
    u32 cu[8], su[8];
    #pragma unroll
    for (int j = 0; j < 8; j++) {
        float s, c;
        __sincosf(v[j], &s, &c);
        cu[j] = f2bf(c);
        su[j] = f2bf(s);
    }
    *(int4*)(base + pc) = make_int4(
        (int)(cu[0] | (cu[1] << 16)), (int)(cu[2] | (cu[3] << 16)),
        (int)(cu[4] | (cu[5] << 16)), (int)(cu[6] | (cu[7] << 16)));
    *(int4*)(base + (pc ^ 128)) = make_int4(
        (int)(su[0] | (su[1] << 16)), (int)(su[2] | (su[3] << 16)),
        (int)(su[4] | (su[5] << 16)), (int)(su[6] | (su[7] << 16)));
}

__global__ void __launch_bounds__(256)
pci_kernel(const float* __restrict__ ph, float* __restrict__ slabs)
{
    __shared__ char lds[32768];          // A tile 16 KB | B tile 16 KB
    char* la = lds;
    char* lb = lds + 16384;

    // bijective XCD swizzle (NBLK % 8 == 0)
    const int bid = blockIdx.x;
    const int l   = (bid & 7) * (NBLK / 8) + (bid >> 3);
    const int h   = l & 3;                   // K-split index 0..3
    const int t4  = l >> 2;
    const int pos = t4 % NPOS;               // symmetric tile position
    const int y   = t4 / NPOS;               // batch
    const int i0 = TI_[pos] * 64, j0 = TJ_[pos] * 64;
    const bool diag = (i0 == j0);
    char* lbp = diag ? la : lb;              // diagonal: B-fragments from la

    const int t    = threadIdx.x;
    const int lane = t & 63, w = t >> 6;
    const int wrow = (w >> 1) * 32, wcol = (w & 1) * 32;
    const int m = lane & 15, q = lane >> 4;

    // staging assignment: thread t covers (row0, oct) and (row1=row0+32, oct);
    // oct covers k = h*512 + it*64 + oct*8 .. +7 (8 consecutive f32 phases)
    const int row0 = t >> 3, oct = t & 7;    // row0 in [0,32), oct in [0,8)
    const int row1 = row0 + 32;
    const float* gA0 = ph + ((size_t)(y * 256 + i0 + row0) * 2048 + h * 512 + oct * 8);
    const float* gA1 = ph + ((size_t)(y * 256 + i0 + row1) * 2048 + h * 512 + oct * 8);
    const float* gB0 = ph + ((size_t)(y * 256 + j0 + row0) * 2048 + h * 512 + oct * 8);
    const float* gB1 = ph + ((size_t)(y * 256 + j0 + row1) * 2048 + h * 512 + oct * 8);
    char* dA0 = la + row0 * 256;  const int pc0 = (oct ^ (row0 & 15)) * 16;
    char* dA1 = la + row1 * 256;  const int pc1 = (oct ^ (row1 & 15)) * 16;
    char* dB0 = lb + row0 * 256;
    char* dB1 = lb + row1 * 256;

    f32x4 zero = {0.f, 0.f, 0.f, 0.f};
    f32x4 accR[2][2], accSC[2][2], accCS[2][2];
    #pragma unroll
    for (int a = 0; a < 2; a++)
        #pragma unroll
        for (int c = 0; c < 2; c++) {
            accR[a][c] = zero; accSC[a][c] = zero; accCS[a][c] = zero;
        }

    for (int it = 0; it < 8; ++it) {         // 8 iters x BK=64 = K/4
        __syncthreads();                     // protect LDS from prior reads
        float4 a0 = *(const float4*)gA0, a1 = *(const float4*)(gA0 + 4);
        float4 a2 = *(const float4*)gA1, a3 = *(const float4*)(gA1 + 4);
        float4 b0, b1, b2, b3;
        if (!diag) {                         // block-uniform branch
            b0 = *(const float4*)gB0; b1 = *(const float4*)(gB0 + 4);
            b2 = *(const float4*)gB1; b3 = *(const float4*)(gB1 + 4);
        }
        gA0 += 64; gA1 += 64; gB0 += 64; gB1 += 64;
        stage8(a0, a1, dA0, pc0);
        stage8(a2, a3, dA1, pc1);
        if (!diag) {
            stage8(b0, b1, dB0, pc0);
            stage8(b2, b3, dB1, pc1);
        }
        __syncthreads();                     // ds_writes visible to all waves

        #pragma unroll
        for (int s = 0; s < 2; ++s) {
            bf16x8 fac[2], fas[2], fbc[2], fbs[2];
            #pragma unroll
            for (int a = 0; a < 2; a++) {
                const char* base = la + (wrow + a * 16 + m) * 256;
                int pc = ((4 * s + q) ^ m) * 16;     // cos physical chunk
                fac[a] = *(const bf16x8*)(base + pc);
                fas[a] = *(const bf16x8*)(base + (pc ^ 128)); // sin = cos ^ bit3
            }
            #pragma unroll
            for (int c = 0; c < 2; c++) {
                const char* base = lbp + (wcol + c * 16 + m) * 256;
                int pc = ((4 * s + q) ^ m) * 16;
                fbc[c] = *(const bf16x8*)(base + pc);
                fbs[c] = *(const bf16x8*)(base + (pc ^ 128));
            }
            #pragma unroll
            for (int a = 0; a < 2; a++)
                #pragma unroll
                for (int c = 0; c < 2; c++) {
                    accR[a][c]  = __builtin_amdgcn_mfma_f32_16x16x32_bf16(fac[a], fbc[c], accR[a][c], 0, 0, 0);
                    accR[a][c]  = __builtin_amdgcn_mfma_f32_16x16x32_bf16(fas[a], fbs[c], accR[a][c], 0, 0, 0);
                    accSC[a][c] = __builtin_amdgcn_mfma_f32_16x16x32_bf16(fas[a], fbc[c], accSC[a][c], 0, 0, 0);
                    accCS[a][c] = __builtin_amdgcn_mfma_f32_16x16x32_bf16(fac[a], fbs[c], accCS[a][c], 0, 0, 0);
                }
        }
    }

    // epilogue: deterministic slab stores, interleaved (re, im) float2
    float* sl = slabs + (size_t)h * ((size_t)NRED * 2)
                      + (size_t)(y * NPOS + pos) * 8192;
    #pragma unroll
    for (int a = 0; a < 2; a++)
        #pragma unroll
        for (int c = 0; c < 2; c++) {
            int ii = wrow + a * 16 + q * 4;      // C/D: row=(lane>>4)*4+reg
            int jj = wcol + c * 16 + m;          // C/D: col=lane&15
            #pragma unroll
            for (int r = 0; r < 4; r++) {
                int idx = (ii + r) * 64 + jj;
                float2 v = make_float2(accR[a][c][r], accSC[a][c][r] - accCS[a][c][r]);
                *(float2*)(sl + (size_t)idx * 2) = v;
            }
        }
}

// ---------------------------------------------------------------------------
// Kernel B2: sum 4 K-split slabs -> pci -> squared error vs target(s).
// Off-diagonal tiles contribute both (i,j) and (j,i) target terms (pci is
// symmetric so p is shared); pos is uniform per wave -> no divergence.
// ---------------------------------------------------------------------------
__global__ void __launch_bounds__(256)
coh_kernel(const float* __restrict__ slabs, const float* __restrict__ tgt,
           float* __restrict__ accum)
{
    __shared__ float sred[4];
    const int tid  = blockIdx.x * 256 + threadIdx.x;
    const int e0   = tid * 8;                // 8 consecutive elems, one row
    const int tile = e0 >> 12;
    const int y    = tile / NPOS;
    const int pos  = tile % NPOS;
    const int ii   = (e0 & 4095) >> 6;
    const int jj0  = e0 & 63;
    const int ig   = TI_[pos] * 64 + ii;
    const int jg   = TJ_[pos] * 64 + jj0;
    const bool off = (pos >= 4);
    const float invf = 1.0f / (float)F_;
    const float* ty = tgt + (size_t)y * (C_ * C_);
    const float* tr = ty + ig * C_ + jg;

    float rv[8] = {0.f, 0.f, 0.f, 0.f, 0.f, 0.f, 0.f, 0.f};
    float iv[8] = {0.f, 0.f, 0.f, 0.f, 0.f, 0.f, 0.f, 0.f};
    #pragma unroll
    for (int hh = 0; hh < 4; hh++) {
        const float* s = slabs + (size_t)hh * ((size_t)NRED * 2) + (size_t)e0 * 2;
        float4 v0 = *(const float4*)(s);
        float4 v1 = *(const float4*)(s + 4);
        float4 v2 = *(const float4*)(s + 8);
        float4 v3 = *(const float4*)(s + 12);
        rv[0] += v0.x; iv[0] += v0.y; rv[1] += v0.z; iv[1] += v0.w;
        rv[2] += v1.x; iv[2] += v1.y; rv[3] += v1.z; iv[3] += v1.w;
        rv[4] += v2.x; iv[4] += v2.y; rv[5] += v2.z; iv[5] += v2.w;
        rv[6] += v3.x; iv[6] += v3.y; rv[7] += v3.z; iv[7] += v3.w;
    }

    float coh = 0.f;
    #pragma unroll
    for (int j = 0; j < 8; j++) {
        float re = rv[j] * invf, im = iv[j] * invf;
        float p  = sqrtf(re * re + im * im + EPS_);
        float d  = p - tr[j];
        coh += d * d;
        if (off) { float d2 = p - ty[(jg + j) * C_ + ig]; coh += d2 * d2; }
    }

    #pragma unroll
    for (int o = 32; o > 0; o >>= 1) coh += __shfl_down(coh, o, 64);
    int lane = threadIdx.x & 63, w = threadIdx.x >> 6;
    if (lane == 0) sred[w] = coh;
    __syncthreads();
    if (threadIdx.x == 0)
        atomicAdd(&accum[2], sred[0] + sred[1] + sred[2] + sred[3]);
}

// ---------------------------------------------------------------------------
// Kernel C: finalize the 4 scalars
// ---------------------------------------------------------------------------
__global__ void fin_kernel(const float* __restrict__ accum, float* __restrict__ out)
{
    if (threadIdx.x == 0) {
        float mag = accum[0] * (1.0f / (float)NTOT);
        float phs = accum[1] * (1.0f / (float)NTOT);
        float coh = accum[2] * (1.0f / (float)NCC);
        out[0] = ALPHA_ * mag + BETA_ * phs + GAMMA_ * coh;
        out[1] = mag;
        out[2] = phs;
        out[3] = coh;
    }
}

extern "C" void kernel_launch(void* const* d_in, const int* in_sizes, int n_in,
                              void* d_out, int out_size, void* d_ws, size_t ws_size,
                              hipStream_t stream)
{
    const float* mh  = (const float*)d_in[0];
    const float* ph  = (const float*)d_in[1];
    const float* mt  = (const float*)d_in[2];
    const float* pt  = (const float*)d_in[3];
    const float* tgt = (const float*)d_in[4];
    float* out = (float*)d_out;

    // ws layout: [0..3] float accumulators | slabs 4 x (NRED x float2) = 41.9 MB
    float* accum = (float*)d_ws;
    float* slabs = (float*)((char*)d_ws + 256);

    hipMemsetAsync(d_ws, 0, 16, stream);     // scalars only; slabs fully written

    ew_kernel<<<1024, 256, 0, stream>>>(
        (const float4*)mh, (const float4*)ph, (const float4*)mt, (const float4*)pt,
        accum);

    pci_kernel<<<NBLK, 256, 0, stream>>>(ph, slabs);

    coh_kernel<<<640, 256, 0, stream>>>(slabs, tgt, accum);

    fin_kernel<<<1, 64, 0, stream>>>(accum, out);
}

// Round 4
// 299.949 us; speedup vs baseline: 1.0698x; 1.0286x over previous
//
#include <hip/hip_runtime.h>
#include <hip/hip_bf16.h>

#define ALPHA_ 1.0f
#define BETA_  0.5f
#define GAMMA_ 0.3f
#define EPS_   1e-8f

typedef unsigned short u16;
typedef unsigned int u32;

constexpr int B_ = 32, C_ = 256, F_ = 2048;
constexpr int NTOT = B_ * C_ * F_;          // 16777216
constexpr int NCC  = B_ * C_ * C_;          // 2097152
constexpr int NPOS = 10;                    // ti<=tj positions in 4x4 tile grid
constexpr int KSPL = 4;                     // K-split factor (K=2048 -> 4x512)
constexpr int NBLK = B_ * NPOS * KSPL;      // 1280 pci blocks (1280 % 8 == 0)
constexpr int NRED = B_ * NPOS * 64 * 64;   // 1310720 partial re/im elements

// symmetric tile positions: 4 diagonal first, then 6 strict-upper
__constant__ int TI_[NPOS] = {0, 1, 2, 3, 0, 0, 0, 1, 1, 2};
__constant__ int TJ_[NPOS] = {0, 1, 2, 3, 1, 2, 3, 2, 3, 3};

typedef __bf16 bf16x8 __attribute__((ext_vector_type(8)));
typedef float  f32x4  __attribute__((ext_vector_type(4)));

// round-to-nearest-even float -> bf16 bits (sin/cos inputs, no NaN/Inf)
__device__ __forceinline__ u32 f2bf(float x) {
    unsigned u = __float_as_uint(x);
    u += 0x7fffu + ((u >> 16) & 1u);
    return (u >> 16);
}

// ---------------------------------------------------------------------------
// Kernel A: elementwise mag/phase losses, PURE-TLP form.
// Rounds 1+3 proved hipcc won't hold a deep per-wave load pipeline (it
// re-hoists compute inside scheduling regions; VGPR stayed 32-40). So get
// MLP from wave count instead: 8192 blocks x 256 thr = 2.1M threads, one
// 8-elem group each, 8 naturally-independent float4 loads, ~48 VGPR ->
// 32 waves/CU. This is the copy-ubench regime (6.3 TB/s).
// Final reduction sharded over 64 partial slots to avoid 8192 same-address
// f32 atomic RMWs serializing at one L2 address.
// ---------------------------------------------------------------------------
__device__ __forceinline__ void ew_body(
    float4 p0, float4 p1, float4 q0, float4 q1,
    float4 a0, float4 a1, float4 b0, float4 b1,
    float& msum, float& psum)
{
    float pv[8] = {p0.x, p0.y, p0.z, p0.w, p1.x, p1.y, p1.z, p1.w};
    float qv[8] = {q0.x, q0.y, q0.z, q0.w, q1.x, q1.y, q1.z, q1.w};
    float av[8] = {a0.x, a0.y, a0.z, a0.w, a1.x, a1.y, a1.z, a1.w};
    float bv[8] = {b0.x, b0.y, b0.z, b0.w, b1.x, b1.y, b1.z, b1.w};
    #pragma unroll
    for (int j = 0; j < 8; j++) {
        float dm = av[j] - bv[j];
        msum += dm * dm;
        psum += 1.f - __cosf(pv[j] - qv[j]);
    }
}

__global__ void __launch_bounds__(256)
ew_kernel(const float4* __restrict__ mh, const float4* __restrict__ ph,
          const float4* __restrict__ mt, const float4* __restrict__ pt,
          float* __restrict__ part)
{
    __shared__ float sm[4], sp[4];
    const int g = blockIdx.x * 256 + threadIdx.x;   // 0..2097151
    float4 p0 = ph[2*g], p1 = ph[2*g+1];
    float4 q0 = pt[2*g], q1 = pt[2*g+1];
    float4 a0 = mh[2*g], a1 = mh[2*g+1];
    float4 b0 = mt[2*g], b1 = mt[2*g+1];

    float msum = 0.f, psum = 0.f;
    ew_body(p0, p1, q0, q1, a0, a1, b0, b1, msum, psum);

    #pragma unroll
    for (int o = 32; o > 0; o >>= 1) {
        msum += __shfl_down(msum, o, 64);
        psum += __shfl_down(psum, o, 64);
    }
    int lane = threadIdx.x & 63, wv = threadIdx.x >> 6;
    if (lane == 0) { sm[wv] = msum; sp[wv] = psum; }
    __syncthreads();
    if (threadIdx.x == 0) {
        int slot = blockIdx.x & 63;                 // 128 blocks per slot
        atomicAdd(&part[slot],      sm[0] + sm[1] + sm[2] + sm[3]);
        atomicAdd(&part[64 + slot], sp[0] + sp[1] + sp[2] + sp[3]);
    }
}

// ---------------------------------------------------------------------------
// Kernel B: batched MFMA partial re/im, SYMMETRIC tile set, K-split 4.
// (UNCHANGED from round-3-verified version; with ew/coh shrunk this becomes
// the top dispatch next round and gets real counters before being edited.)
// Staging reg-staged directly from phase_hat: load 8 phases, sincos -> bf16
// pack -> swizzled ds_write_b128 pair (cos chunk, sin = ^128). Diagonal
// blocks stage one panel; epilogue is deterministic slab float2 stores.
// ---------------------------------------------------------------------------
__device__ __forceinline__ void stage8(float4 a, float4 b, char* base, int pc) {
    float v[8] = {a.x, a.y, a.z, a.w, b.x, b.y, b.z, b.w};
    u32 cu[8], su[8];
    #pragma unroll
    for (int j = 0; j < 8; j++) {
        float s, c;
        __sincosf(v[j], &s, &c);
        cu[j] = f2bf(c);
        su[j] = f2bf(s);
    }
    *(int4*)(base + pc) = make_int4(
        (int)(cu[0] | (cu[1] << 16)), (int)(cu[2] | (cu[3] << 16)),
        (int)(cu[4] | (cu[5] << 16)), (int)(cu[6] | (cu[7] << 16)));
    *(int4*)(base + (pc ^ 128)) = make_int4(
        (int)(su[0] | (su[1] << 16)), (int)(su[2] | (su[3] << 16)),
        (int)(su[4] | (su[5] << 16)), (int)(su[6] | (su[7] << 16)));
}

__global__ void __launch_bounds__(256)
pci_kernel(const float* __restrict__ ph, float* __restrict__ slabs)
{
    __shared__ char lds[32768];          // A tile 16 KB | B tile 16 KB
    char* la = lds;
    char* lb = lds + 16384;

    // bijective XCD swizzle (NBLK % 8 == 0)
    const int bid = blockIdx.x;
    const int l   = (bid & 7) * (NBLK / 8) + (bid >> 3);
    const int h   = l & 3;                   // K-split index 0..3
    const int t4  = l >> 2;
    const int pos = t4 % NPOS;               // symmetric tile position
    const int y   = t4 / NPOS;               // batch
    const int i0 = TI_[pos] * 64, j0 = TJ_[pos] * 64;
    const bool diag = (i0 == j0);
    char* lbp = diag ? la : lb;              // diagonal: B-fragments from la

    const int t    = threadIdx.x;
    const int lane = t & 63, w = t >> 6;
    const int wrow = (w >> 1) * 32, wcol = (w & 1) * 32;
    const int m = lane & 15, q = lane >> 4;

    // staging: thread t covers (row0, oct) and (row1=row0+32, oct);
    // oct covers k = h*512 + it*64 + oct*8 .. +7
    const int row0 = t >> 3, oct = t & 7;
    const int row1 = row0 + 32;
    const float* gA0 = ph + ((size_t)(y * 256 + i0 + row0) * 2048 + h * 512 + oct * 8);
    const float* gA1 = ph + ((size_t)(y * 256 + i0 + row1) * 2048 + h * 512 + oct * 8);
    const float* gB0 = ph + ((size_t)(y * 256 + j0 + row0) * 2048 + h * 512 + oct * 8);
    const float* gB1 = ph + ((size_t)(y * 256 + j0 + row1) * 2048 + h * 512 + oct * 8);
    char* dA0 = la + row0 * 256;  const int pc0 = (oct ^ (row0 & 15)) * 16;
    char* dA1 = la + row1 * 256;  const int pc1 = (oct ^ (row1 & 15)) * 16;
    char* dB0 = lb + row0 * 256;
    char* dB1 = lb + row1 * 256;

    f32x4 zero = {0.f, 0.f, 0.f, 0.f};
    f32x4 accR[2][2], accSC[2][2], accCS[2][2];
    #pragma unroll
    for (int a = 0; a < 2; a++)
        #pragma unroll
        for (int c = 0; c < 2; c++) {
            accR[a][c] = zero; accSC[a][c] = zero; accCS[a][c] = zero;
        }

    for (int it = 0; it < 8; ++it) {         // 8 iters x BK=64 = K/4
        __syncthreads();                     // protect LDS from prior reads
        float4 a0 = *(const float4*)gA0, a1 = *(const float4*)(gA0 + 4);
        float4 a2 = *(const float4*)gA1, a3 = *(const float4*)(gA1 + 4);
        float4 b0, b1, b2, b3;
        if (!diag) {                         // block-uniform branch
            b0 = *(const float4*)gB0; b1 = *(const float4*)(gB0 + 4);
            b2 = *(const float4*)gB1; b3 = *(const float4*)(gB1 + 4);
        }
        gA0 += 64; gA1 += 64; gB0 += 64; gB1 += 64;
        stage8(a0, a1, dA0, pc0);
        stage8(a2, a3, dA1, pc1);
        if (!diag) {
            stage8(b0, b1, dB0, pc0);
            stage8(b2, b3, dB1, pc1);
        }
        __syncthreads();                     // ds_writes visible to all waves

        #pragma unroll
        for (int s = 0; s < 2; ++s) {
            bf16x8 fac[2], fas[2], fbc[2], fbs[2];
            #pragma unroll
            for (int a = 0; a < 2; a++) {
                const char* base = la + (wrow + a * 16 + m) * 256;
                int pc = ((4 * s + q) ^ m) * 16;     // cos physical chunk
                fac[a] = *(const bf16x8*)(base + pc);
                fas[a] = *(const bf16x8*)(base + (pc ^ 128)); // sin = cos ^ bit3
            }
            #pragma unroll
            for (int c = 0; c < 2; c++) {
                const char* base = lbp + (wcol + c * 16 + m) * 256;
                int pc = ((4 * s + q) ^ m) * 16;
                fbc[c] = *(const bf16x8*)(base + pc);
                fbs[c] = *(const bf16x8*)(base + (pc ^ 128));
            }
            #pragma unroll
            for (int a = 0; a < 2; a++)
                #pragma unroll
                for (int c = 0; c < 2; c++) {
                    accR[a][c]  = __builtin_amdgcn_mfma_f32_16x16x32_bf16(fac[a], fbc[c], accR[a][c], 0, 0, 0);
                    accR[a][c]  = __builtin_amdgcn_mfma_f32_16x16x32_bf16(fas[a], fbs[c], accR[a][c], 0, 0, 0);
                    accSC[a][c] = __builtin_amdgcn_mfma_f32_16x16x32_bf16(fas[a], fbc[c], accSC[a][c], 0, 0, 0);
                    accCS[a][c] = __builtin_amdgcn_mfma_f32_16x16x32_bf16(fac[a], fbs[c], accCS[a][c], 0, 0, 0);
                }
        }
    }

    // epilogue: deterministic slab stores, interleaved (re, im) float2
    float* sl = slabs + (size_t)h * ((size_t)NRED * 2)
                      + (size_t)(y * NPOS + pos) * 8192;
    #pragma unroll
    for (int a = 0; a < 2; a++)
        #pragma unroll
        for (int c = 0; c < 2; c++) {
            int ii = wrow + a * 16 + q * 4;      // C/D: row=(lane>>4)*4+reg
            int jj = wcol + c * 16 + m;          // C/D: col=lane&15
            #pragma unroll
            for (int r = 0; r < 4; r++) {
                int idx = (ii + r) * 64 + jj;
                float2 v = make_float2(accR[a][c][r], accSC[a][c][r] - accCS[a][c][r]);
                *(float2*)(sl + (size_t)idx * 2) = v;
            }
        }
}

// ---------------------------------------------------------------------------
// Kernel B2: per-tile blocks; sum 4 K-split slabs -> pci -> LDS [64][65] ->
// BOTH loss passes with fully-coalesced tgt reads. The old version's 10M
// stride-1KB scalar gathers (ty[(jg+j)*C+ig], 64B line each, 2.5 blk/CU)
// are replaced by an LDS transpose: pass 2 reads p^T from LDS (65-pad ->
// ~2-way conflicts) while tgt rows are read contiguously.
// Grid: 320 blocks (one per (batch, pos) tile).
// ---------------------------------------------------------------------------
__global__ void __launch_bounds__(256)
coh_kernel(const float* __restrict__ slabs, const float* __restrict__ tgt,
           float* __restrict__ accum)
{
    __shared__ float pl[64 * 65];            // padded 64x64 pci tile
    __shared__ float sred[4];
    const int blk = blockIdx.x;              // 0..319
    const int y   = blk / NPOS;
    const int pos = blk % NPOS;
    const int t   = threadIdx.x;
    const bool off = (pos >= 4);
    const float invf = 1.0f / (float)F_;
    const int ib = TI_[pos] * 64, jb = TJ_[pos] * 64;
    const float* ty = tgt + (size_t)y * (C_ * C_);
    const size_t sb0 = (size_t)(y * NPOS + pos) * 8192;

    float coh = 0.f;
    // elem pairs e = 2t + k*512 (8 chunks x 2 elems = 16 elems/thread)
    #pragma unroll
    for (int k = 0; k < 8; ++k) {
        int e = 2 * t + k * 512;
        float r0 = 0.f, s0 = 0.f, r1 = 0.f, s1 = 0.f;
        #pragma unroll
        for (int hh = 0; hh < 4; ++hh) {
            float4 v = *(const float4*)(slabs
                + (size_t)hh * ((size_t)NRED * 2) + sb0 + (size_t)e * 2);
            r0 += v.x; s0 += v.y; r1 += v.z; s1 += v.w;
        }
        float re0 = r0 * invf, im0 = s0 * invf;
        float re1 = r1 * invf, im1 = s1 * invf;
        float p0 = sqrtf(re0 * re0 + im0 * im0 + EPS_);
        float p1 = sqrtf(re1 * re1 + im1 * im1 + EPS_);
        int ii = e >> 6, jj = e & 63;
        pl[ii * 65 + jj]     = p0;
        pl[ii * 65 + jj + 1] = p1;
        // pass 1: tile (ib+ii, jb+jj..+1), coalesced float2 target read
        float2 tg = *(const float2*)(ty + (size_t)(ib + ii) * C_ + jb + jj);
        float d0 = p0 - tg.x, d1 = p1 - tg.y;
        coh += d0 * d0 + d1 * d1;
    }
    __syncthreads();

    if (off) {
        // pass 2: mirror tile rows jb+ii, cols ib+jj..+1; p^T from LDS
        #pragma unroll
        for (int k = 0; k < 8; ++k) {
            int e = 2 * t + k * 512;
            int ii = e >> 6, jj = e & 63;    // (row ii, col jj) of mirror tile
            float p0 = pl[jj * 65 + ii];         // p[jj][ii]
            float p1 = pl[(jj + 1) * 65 + ii];
            float2 tg = *(const float2*)(ty + (size_t)(jb + ii) * C_ + ib + jj);
            float d0 = p0 - tg.x, d1 = p1 - tg.y;
            coh += d0 * d0 + d1 * d1;
        }
    }

    #pragma unroll
    for (int o = 32; o > 0; o >>= 1) coh += __shfl_down(coh, o, 64);
    int lane = t & 63, w = t >> 6;
    if (lane == 0) sred[w] = coh;
    __syncthreads();
    if (t == 0)
        atomicAdd(&accum[2], sred[0] + sred[1] + sred[2] + sred[3]);
}

// ---------------------------------------------------------------------------
// Kernel C: finalize — sum the 64+64 ew partial slots + coh scalar
// ---------------------------------------------------------------------------
__global__ void fin_kernel(const float* __restrict__ accum,
                           const float* __restrict__ part,
                           float* __restrict__ out)
{
    int t = threadIdx.x;                     // 64 threads
    float m = part[t], p = part[64 + t];
    #pragma unroll
    for (int o = 32; o > 0; o >>= 1) {
        m += __shfl_down(m, o, 64);
        p += __shfl_down(p, o, 64);
    }
    if (t == 0) {
        float mag = m * (1.0f / (float)NTOT);
        float phs = p * (1.0f / (float)NTOT);
        float coh = accum[2] * (1.0f / (float)NCC);
        out[0] = ALPHA_ * mag + BETA_ * phs + GAMMA_ * coh;
        out[1] = mag;
        out[2] = phs;
        out[3] = coh;
    }
}

extern "C" void kernel_launch(void* const* d_in, const int* in_sizes, int n_in,
                              void* d_out, int out_size, void* d_ws, size_t ws_size,
                              hipStream_t stream)
{
    const float* mh  = (const float*)d_in[0];
    const float* ph  = (const float*)d_in[1];
    const float* mt  = (const float*)d_in[2];
    const float* pt  = (const float*)d_in[3];
    const float* tgt = (const float*)d_in[4];
    float* out = (float*)d_out;

    // ws layout: accum[0..3] @0 | part[128] @256 B | slabs @1024 B (41.9 MB)
    float* accum = (float*)d_ws;
    float* part  = (float*)((char*)d_ws + 256);
    float* slabs = (float*)((char*)d_ws + 1024);

    hipMemsetAsync(d_ws, 0, 1024, stream);   // scalars + partial slots

    ew_kernel<<<8192, 256, 0, stream>>>(
        (const float4*)mh, (const float4*)ph, (const float4*)mt, (const float4*)pt,
        part);

    pci_kernel<<<NBLK, 256, 0, stream>>>(ph, slabs);

    coh_kernel<<<320, 256, 0, stream>>>(slabs, tgt, accum);

    fin_kernel<<<1, 64, 0, stream>>>(accum, part, out);
}